// Round 3
// baseline (551.374 us; speedup 1.0000x reference)
//
#include <hip/hip_runtime.h>
#include <hip/hip_bf16.h>

typedef unsigned short u16;
typedef unsigned int   u32;

typedef __bf16 bf16x8 __attribute__((ext_vector_type(8)));
typedef float  f32x4  __attribute__((ext_vector_type(4)));

struct alignas(16) US8 { u16 s[8]; };
struct alignas(8)  US4 { u16 s[4]; };

__device__ __forceinline__ u16 f2bf(float f) {
  u32 x = __builtin_bit_cast(u32, f);
  return (u16)((x + 0x7fffu + ((x >> 16) & 1u)) >> 16);
}
__device__ __forceinline__ bf16x8 ld8(const u16* p) {
  return __builtin_bit_cast(bf16x8, *(const US8*)p);
}
__device__ __forceinline__ f32x4 mfma16(bf16x8 a, bf16x8 b, f32x4 c) {
  return __builtin_amdgcn_mfma_f32_16x16x32_bf16(a, b, c, 0, 0, 0);
}
__device__ __forceinline__ f32x4 zero4() { f32x4 z; z[0]=0.f; z[1]=0.f; z[2]=0.f; z[3]=0.f; return z; }

#define NE     2048
#define DFULL  18432
#define NC     8        // K-chunks for QK^T partials (chunk = 2304)

// ------------------------------------------------------------------
// Weight permutation (f32 -> bf16): W1p[b][oc][kk*16+ic] (K padded to 160),
//                                   W2p[b][oc][kk*128+ic] (K=1152)
// ------------------------------------------------------------------
__global__ void prep_weights(const float* __restrict__ w1q, const float* __restrict__ w1k, const float* __restrict__ w1v,
                             const float* __restrict__ w2q, const float* __restrict__ w2k, const float* __restrict__ w2v,
                             u16* __restrict__ w1p, u16* __restrict__ w2p)
{
  int idx = blockIdx.x * blockDim.x + threadIdx.x;
  int stride = gridDim.x * blockDim.x;
  for (int i = idx; i < 3*128*160; i += stride) {
    int b = i / (128*160); int r = i % (128*160);
    int oc = r / 160, k = r % 160;
    u16 v = 0;
    if (k < 144) {
      int kk = k >> 4, ic = k & 15;
      const float* w = (b == 0) ? w1q : (b == 1) ? w1k : w1v;
      v = f2bf(w[oc*144 + ic*9 + kk]);
    }
    w1p[i] = v;
  }
  for (int i = idx; i < 3*128*1152; i += stride) {
    int b = i / (128*1152); int r = i % (128*1152);
    int oc = r / 1152, k = r % 1152;
    int kk = k >> 7, ic = k & 127;
    const float* w = (b == 0) ? w2q : (b == 1) ? w2k : w2v;
    w2p[i] = f2bf(w[oc*1152 + ic*9 + kk]);
  }
}

// ------------------------------------------------------------------
// Fused conv1(16->128,3x3)+ReLU -> conv2(128->128,3x3)+ReLU per (edge,branch)
// ------------------------------------------------------------------
__global__ __launch_bounds__(256, 2)
void conv_fused(const float* __restrict__ edge_feat,
                const u16* __restrict__ w1p, const u16* __restrict__ w2p,
                const float* __restrict__ b1q, const float* __restrict__ b1k, const float* __restrict__ b1v,
                const float* __restrict__ b2q, const float* __restrict__ b2k, const float* __restrict__ b2v,
                u16* __restrict__ outq, u16* __restrict__ outk, u16* __restrict__ outv)
{
  const int bb = blockIdx.x / NE;   // branch 0=q 1=k 2=v
  const int e  = blockIdx.x % NE;
  const int t = threadIdx.x;
  const int w = t >> 6, l = t & 63;
  const int l15 = l & 15, lq = l >> 4;

  __shared__ __align__(16) u16 x_hwc[4096 + 8];  // [h][w][ic] bf16 + 16B zero pad
  __shared__ __align__(16) u16 h1t[196 * 128];   // [pixel][ic], XOR-swizzled
  __shared__ float b1f[128], b2f[128];

  // stage input tile HWC (f32 global -> bf16 LDS)
  const float* xin = edge_feat + (size_t)e * 4096;
  for (int i = t; i < 1024; i += 256) {          // 1024 float4 units, CHW in global
    float4 u = ((const float4*)xin)[i];
    int c = i >> 6, hw0 = (i & 63) * 4;
    x_hwc[(hw0 + 0)*16 + c] = f2bf(u.x);
    x_hwc[(hw0 + 1)*16 + c] = f2bf(u.y);
    x_hwc[(hw0 + 2)*16 + c] = f2bf(u.z);
    x_hwc[(hw0 + 3)*16 + c] = f2bf(u.w);
  }
  {
    const float* b1p = bb == 0 ? b1q : bb == 1 ? b1k : b1v;
    const float* b2p = bb == 0 ? b2q : bb == 1 ? b2k : b2v;
    if (t < 128) { b1f[t] = b1p[t]; b2f[t] = b2p[t]; }
    if (t < 8) x_hwc[4096 + t] = 0;
  }
  __syncthreads();

  // ---------------- conv1: M=128(oc), N=196(pix)->13 tiles, K=144->160 ----------------
  const u16* W1b = w1p + bb * (128*160);
  f32x4 acc1[2][13];
  #pragma unroll
  for (int mi = 0; mi < 2; ++mi)
    #pragma unroll
    for (int nt = 0; nt < 13; ++nt) acc1[mi][nt] = zero4();

  int offb[13];
  #pragma unroll
  for (int nt = 0; nt < 13; ++nt) {
    int p = nt*16 + l15; if (p > 195) p = 195;
    int y = p / 14, x = p % 14;
    offb[nt] = (y*16 + x) * 16;
  }

  #pragma unroll
  for (int ks = 0; ks < 5; ++ks) {
    int k = ks*32 + lq*8;
    bf16x8 a0 = ld8(W1b + ((w*2 + 0)*16 + l15)*160 + k);
    bf16x8 a1 = ld8(W1b + ((w*2 + 1)*16 + l15)*160 + k);
    int kk = k >> 4;                 // 0..9 (9 => zero padding)
    int ky = kk / 3, kx = kk - ky*3;
    int koff = (ky*16 + kx)*16 + (k & 15);
    bool kvalid = (k < 144);
    #pragma unroll
    for (int nt = 0; nt < 13; ++nt) {
      const u16* bp = kvalid ? (x_hwc + offb[nt] + koff) : (x_hwc + 4096);
      bf16x8 bf = ld8(bp);
      acc1[0][nt] = mfma16(a0, bf, acc1[0][nt]);
      acc1[1][nt] = mfma16(a1, bf, acc1[1][nt]);
    }
  }

  // bias + relu -> h1t [pixel][ic] bf16 with XOR swizzle on 16B blocks
  #pragma unroll
  for (int mi = 0; mi < 2; ++mi)
    #pragma unroll
    for (int nt = 0; nt < 13; ++nt) {
      int p = nt*16 + l15;
      if (p < 196) {
        #pragma unroll
        for (int r = 0; r < 4; ++r) {
          int oc = (w*2 + mi)*16 + lq*4 + r;
          float v = acc1[mi][nt][r] + b1f[oc];
          v = v > 0.f ? v : 0.f;
          int byte = (p*256 + oc*2) ^ ((p & 7) << 4);
          *(u16*)((char*)h1t + byte) = f2bf(v);
        }
      }
    }
  __syncthreads();

  // ---------------- conv2: M=128(oc), N=144(pix)->9 tiles, K=1152 ----------------
  const u16* W2b = w2p + bb * (128*1152);
  f32x4 acc2[2][9];
  #pragma unroll
  for (int mi = 0; mi < 2; ++mi)
    #pragma unroll
    for (int nt = 0; nt < 9; ++nt) acc2[mi][nt] = zero4();

  int pb[9];
  #pragma unroll
  for (int nt = 0; nt < 9; ++nt) {
    int p2 = nt*16 + l15;
    int y2 = p2 / 12, x2 = p2 - y2*12;
    pb[nt] = y2*14 + x2;
  }

  const u16* A0p = W2b + ((w*2 + 0)*16 + l15)*1152;
  const u16* A1p = W2b + ((w*2 + 1)*16 + l15)*1152;
  bf16x8 a0 = ld8(A0p + lq*8);
  bf16x8 a1 = ld8(A1p + lq*8);
  for (int ks = 0; ks < 36; ++ks) {
    int k = ks*32 + lq*8;
    int kn = (ks < 35) ? (k + 32) : (lq*8);    // wrap to valid addr on last iter
    bf16x8 na0 = ld8(A0p + kn);
    bf16x8 na1 = ld8(A1p + kn);
    int kk = k >> 7;                           // (ky,kx) index 0..8
    int ky = kk / 3, kx = kk - ky*3;
    int pk = ky*14 + kx;
    int ic2 = (k & 127) * 2;
    #pragma unroll
    for (int nt = 0; nt < 9; ++nt) {
      int pp = pb[nt] + pk;
      int byte = (pp*256 + ic2) ^ ((pp & 7) << 4);
      bf16x8 bfr = ld8((const u16*)((const char*)h1t + byte));
      acc2[0][nt] = mfma16(a0, bfr, acc2[0][nt]);
      acc2[1][nt] = mfma16(a1, bfr, acc2[1][nt]);
    }
    a0 = na0; a1 = na1;
  }

  u16* outp = bb == 0 ? outq : bb == 1 ? outk : outv;
  u16* oe = outp + (size_t)e * DFULL;
  #pragma unroll
  for (int mi = 0; mi < 2; ++mi)
    #pragma unroll
    for (int nt = 0; nt < 9; ++nt) {
      int p2 = nt*16 + l15;
      #pragma unroll
      for (int r = 0; r < 4; ++r) {
        int oc = (w*2 + mi)*16 + lq*4 + r;
        float v = acc2[mi][nt][r] + b2f[oc];
        v = v > 0.f ? v : 0.f;
        oe[oc*144 + p2] = f2bf(v);
      }
    }
}

// ------------------------------------------------------------------
// S = Q K^T partials: grid (16 g x NC kc), each block K-chunk of 18432/NC
// ------------------------------------------------------------------
__global__ __launch_bounds__(256, 2)
void qk_partial(const u16* __restrict__ Q, const u16* __restrict__ K, float* __restrict__ Sp)
{
  const int g = blockIdx.x / NC, kc = blockIdx.x % NC;
  const int t = threadIdx.x, w = t >> 6, l = t & 63;
  const int l15 = l & 15, lq = l >> 4;
  const int CH = DFULL / NC;                  // 2304
  const u16* Qb = Q + (size_t)g*128*DFULL + kc*CH;
  const u16* Kb = K + (size_t)g*128*DFULL + kc*CH;

  f32x4 acc[2][8];
  #pragma unroll
  for (int mi = 0; mi < 2; ++mi)
    #pragma unroll
    for (int nt = 0; nt < 8; ++nt) acc[mi][nt] = zero4();

  for (int ks = 0; ks < CH/32; ++ks) {
    int k = ks*32 + lq*8;
    bf16x8 a0 = ld8(Qb + (size_t)((w*2 + 0)*16 + l15)*DFULL + k);
    bf16x8 a1 = ld8(Qb + (size_t)((w*2 + 1)*16 + l15)*DFULL + k);
    #pragma unroll
    for (int nt = 0; nt < 8; ++nt) {
      bf16x8 b = ld8(Kb + (size_t)(nt*16 + l15)*DFULL + k);
      acc[0][nt] = mfma16(a0, b, acc[0][nt]);
      acc[1][nt] = mfma16(a1, b, acc[1][nt]);
    }
  }

  float* So = Sp + (size_t)(g*NC + kc)*16384;
  #pragma unroll
  for (int mi = 0; mi < 2; ++mi)
    #pragma unroll
    for (int nt = 0; nt < 8; ++nt) {
      int col = nt*16 + l15;
      #pragma unroll
      for (int r = 0; r < 4; ++r) {
        int row = (w*2 + mi)*16 + lq*4 + r;
        So[row*128 + col] = acc[mi][nt][r];
      }
    }
}

// ------------------------------------------------------------------
// softmax: one wave per (g,n) row; reduce NC partials, scale=1/16
// ------------------------------------------------------------------
__global__ void softmax_p(const float* __restrict__ Sp, u16* __restrict__ P)
{
  const int rr = blockIdx.x;          // 2048 rows
  const int g = rr >> 7, n = rr & 127;
  const int l = threadIdx.x;          // 64
  const float* base = Sp + (size_t)g*NC*16384 + n*128;
  float v0 = 0.f, v1 = 0.f;
  #pragma unroll
  for (int kc = 0; kc < NC; ++kc) {
    v0 += base[(size_t)kc*16384 + l];
    v1 += base[(size_t)kc*16384 + 64 + l];
  }
  v0 *= 0.0625f; v1 *= 0.0625f;       // scale = 1/sqrt(2*128)
  float m = fmaxf(v0, v1);
  #pragma unroll
  for (int s = 32; s; s >>= 1) m = fmaxf(m, __shfl_xor(m, s));
  float e0 = __expf(v0 - m), e1 = __expf(v1 - m);
  float sum = e0 + e1;
  #pragma unroll
  for (int s = 32; s; s >>= 1) sum += __shfl_xor(sum, s);
  float inv = 1.f / sum;
  u16* Pr = P + (size_t)g*16384 + n*128;
  Pr[l]      = f2bf(e0 * inv);
  Pr[64 + l] = f2bf(e1 * inv);
}

// ------------------------------------------------------------------
// O = P V: grid (16 g x 96 d-chunks of 192). V (bf16) in ws; O (f32) -> d_out.
// ------------------------------------------------------------------
__global__ __launch_bounds__(256, 2)
void pv_kernel(const u16* __restrict__ P, const u16* __restrict__ V, float* __restrict__ O)
{
  const int g  = blockIdx.x / 96;
  const int dc = blockIdx.x % 96;
  const int d0 = dc * 192;
  const int t = threadIdx.x, w = t >> 6, l = t & 63;
  const int l15 = l & 15, lq = l >> 4;

  // stride 196 u16 = 392 B: rows 8B-aligned (US4 stores legal); transposed
  // scalar gathers are ~4-way bank conflicts.
  __shared__ __align__(16) u16 Vl[128 * 196];

  const u16* Vg = V + (size_t)g*128*DFULL + d0;
  for (int i = t; i < 6144; i += 256) {          // 8B units: 128 rows x 48
    int m = i / 48, c4 = (i % 48) * 4;
    *(US4*)(Vl + m*196 + c4) = *(const US4*)(Vg + (size_t)m*DFULL + c4);
  }
  __syncthreads();

  const u16* Pg = P + (size_t)g*16384;
  f32x4 acc[2][12];
  #pragma unroll
  for (int mi = 0; mi < 2; ++mi)
    #pragma unroll
    for (int nt = 0; nt < 12; ++nt) acc[mi][nt] = zero4();

  #pragma unroll
  for (int ks = 0; ks < 4; ++ks) {
    int k = ks*32 + lq*8;
    bf16x8 a0 = ld8(Pg + ((w*2 + 0)*16 + l15)*128 + k);
    bf16x8 a1 = ld8(Pg + ((w*2 + 1)*16 + l15)*128 + k);
    #pragma unroll
    for (int nt = 0; nt < 12; ++nt) {
      int d = nt*16 + l15;
      US8 tmp;
      #pragma unroll
      for (int j = 0; j < 8; ++j) tmp.s[j] = Vl[(k + j)*196 + d];
      bf16x8 b = __builtin_bit_cast(bf16x8, tmp);
      acc[0][nt] = mfma16(a0, b, acc[0][nt]);
      acc[1][nt] = mfma16(a1, b, acc[1][nt]);
    }
  }

  float* Og = O + (size_t)g*128*DFULL + d0;
  #pragma unroll
  for (int mi = 0; mi < 2; ++mi)
    #pragma unroll
    for (int nt = 0; nt < 12; ++nt) {
      int d = nt*16 + l15;
      #pragma unroll
      for (int r = 0; r < 4; ++r) {
        int n = (w*2 + mi)*16 + lq*4 + r;
        Og[(size_t)n*DFULL + d] = acc[mi][nt][r];
      }
    }
}

// ------------------------------------------------------------------
extern "C" void kernel_launch(void* const* d_in, const int* in_sizes, int n_in,
                              void* d_out, int out_size, void* d_ws, size_t ws_size,
                              hipStream_t stream)
{
  const float* edge_feat = (const float*)d_in[0];
  const float* qw1 = (const float*)d_in[2];
  const float* qb1 = (const float*)d_in[3];
  const float* qw2 = (const float*)d_in[4];
  const float* qb2 = (const float*)d_in[5];
  const float* kw1 = (const float*)d_in[6];
  const float* kb1 = (const float*)d_in[7];
  const float* kw2 = (const float*)d_in[8];
  const float* kb2 = (const float*)d_in[9];
  const float* vw1 = (const float*)d_in[10];
  const float* vb1 = (const float*)d_in[11];
  const float* vw2 = (const float*)d_in[12];
  const float* vb2 = (const float*)d_in[13];

  // d_out (f32, 150,994,944 B) temporarily hosts Q,K as bf16 (exactly fills it),
  // then pv overwrites it with the f32 output.
  u16* Qd = (u16*)d_out;
  u16* Kd = (u16*)d_out + (size_t)NE*DFULL;     // byte offset 75,497,472

  // Workspace layout (~85.4 MB):
  char* ws = (char*)d_ws;
  u16*   W1p = (u16*)  (ws + 0);           //    122,880 B
  u16*   W2p = (u16*)  (ws + 122880);      //    884,736 B
  u16*   Vb  = (u16*)  (ws + 1007616);     // 75,497,472 B
  float* Sp  = (float*)(ws + 76505088);    //  8,388,608 B
  u16*   P   = (u16*)  (ws + 84893696);    //    524,288 B (end 85,417,984)

  prep_weights<<<240, 256, 0, stream>>>(qw1, kw1, vw1, qw2, kw2, vw2, W1p, W2p);
  conv_fused<<<3*NE, 256, 0, stream>>>(edge_feat, W1p, W2p,
                                       qb1, kb1, vb1, qb2, kb2, vb2,
                                       Qd, Kd, Vb);
  qk_partial<<<16*NC, 256, 0, stream>>>(Qd, Kd, Sp);
  softmax_p<<<2048, 64, 0, stream>>>(Sp, P);
  pv_kernel<<<16*96, 256, 0, stream>>>(P, Vb, (float*)d_out);
}

// Round 4
// 427.288 us; speedup vs baseline: 1.2904x; 1.2904x over previous
//
#include <hip/hip_runtime.h>
#include <hip/hip_bf16.h>

typedef unsigned short u16;
typedef unsigned int   u32;

typedef __bf16 bf16x8 __attribute__((ext_vector_type(8)));
typedef float  f32x4  __attribute__((ext_vector_type(4)));

struct alignas(16) US8  { u16 s[8]; };
struct alignas(8)  US4  { u16 s[4]; };
struct alignas(16) UI4  { u32 d[4]; };
struct alignas(8)  U32x2{ u32 x, y; };

__device__ __forceinline__ u16 f2bf(float f) {
  u32 x = __builtin_bit_cast(u32, f);
  return (u16)((x + 0x7fffu + ((x >> 16) & 1u)) >> 16);
}
__device__ __forceinline__ u32 cvtpk(float a, float b) {
  u32 r;
  asm("v_cvt_pk_bf16_f32 %0, %1, %2" : "=v"(r) : "v"(a), "v"(b));
  return r;
}
__device__ __forceinline__ bf16x8 ld8(const u16* p) {
  return __builtin_bit_cast(bf16x8, *(const US8*)p);
}
__device__ __forceinline__ f32x4 mfma16(bf16x8 a, bf16x8 b, f32x4 c) {
  return __builtin_amdgcn_mfma_f32_16x16x32_bf16(a, b, c, 0, 0, 0);
}
__device__ __forceinline__ f32x4 zero4() { f32x4 z; z[0]=0.f; z[1]=0.f; z[2]=0.f; z[3]=0.f; return z; }

#define NE     2048
#define DFULL  18432
#define XROW   24            // x_hwc row stride in u16 (48 B): 3t mod 8 bijective -> conflict-free

// ------------------------------------------------------------------
// Weight permutation (f32 -> bf16): W1p[b][oc][kk*16+ic] (K padded to 160),
//                                   W2p[b][oc][kk*128+ic] (K=1152)
// ------------------------------------------------------------------
__global__ void prep_weights(const float* __restrict__ w1q, const float* __restrict__ w1k, const float* __restrict__ w1v,
                             const float* __restrict__ w2q, const float* __restrict__ w2k, const float* __restrict__ w2v,
                             u16* __restrict__ w1p, u16* __restrict__ w2p)
{
  int idx = blockIdx.x * blockDim.x + threadIdx.x;
  int stride = gridDim.x * blockDim.x;
  for (int i = idx; i < 3*128*160; i += stride) {
    int b = i / (128*160); int r = i % (128*160);
    int oc = r / 160, k = r % 160;
    u16 v = 0;
    if (k < 144) {
      int kk = k >> 4, ic = k & 15;
      const float* w = (b == 0) ? w1q : (b == 1) ? w1k : w1v;
      v = f2bf(w[oc*144 + ic*9 + kk]);
    }
    w1p[i] = v;
  }
  for (int i = idx; i < 3*128*1152; i += stride) {
    int b = i / (128*1152); int r = i % (128*1152);
    int oc = r / 1152, k = r % 1152;
    int kk = k >> 7, ic = k & 127;
    const float* w = (b == 0) ? w2q : (b == 1) ? w2k : w2v;
    w2p[i] = f2bf(w[oc*1152 + ic*9 + kk]);
  }
}

// ------------------------------------------------------------------
// Fused conv1(16->128,3x3)+ReLU -> conv2(128->128,3x3)+ReLU per (edge,branch)
// ------------------------------------------------------------------
__global__ __launch_bounds__(256, 2)
void conv_fused(const float* __restrict__ edge_feat,
                const u16* __restrict__ w1p, const u16* __restrict__ w2p,
                const float* __restrict__ b1q, const float* __restrict__ b1k, const float* __restrict__ b1v,
                const float* __restrict__ b2q, const float* __restrict__ b2k, const float* __restrict__ b2v,
                u16* __restrict__ outq, u16* __restrict__ outk, u16* __restrict__ outv)
{
  const int bb = blockIdx.x / NE;   // branch 0=q 1=k 2=v
  const int e  = blockIdx.x % NE;
  const int t = threadIdx.x;
  const int w = t >> 6, l = t & 63;
  const int l15 = l & 15, lq = l >> 4;

  __shared__ __align__(16) u16 x_hwc[256*XROW + 8];  // [pixel][ch 0..15 + pad], + 16B zeros
  __shared__ __align__(16) u16 h1t[196 * 128];       // [pixel][ic], XOR-swizzled 16B blocks
  __shared__ float b1f[128], b2f[128];

  // ---- stage input: thread t owns pixel t; coalesced f32 loads; conflict-free b128 writes
  {
    const float* xin = edge_feat + (size_t)e * 4096 + t;
    float v[16];
    #pragma unroll
    for (int c = 0; c < 16; ++c) v[c] = xin[c*256];
    UI4 lo_, hi_;
    #pragma unroll
    for (int i = 0; i < 4; ++i) lo_.d[i] = cvtpk(v[2*i],   v[2*i+1]);
    #pragma unroll
    for (int i = 0; i < 4; ++i) hi_.d[i] = cvtpk(v[8+2*i], v[8+2*i+1]);
    *(UI4*)(x_hwc + t*XROW)     = lo_;
    *(UI4*)(x_hwc + t*XROW + 8) = hi_;
  }
  {
    const float* b1p = bb == 0 ? b1q : bb == 1 ? b1k : b1v;
    const float* b2p = bb == 0 ? b2q : bb == 1 ? b2k : b2v;
    if (t < 128) { b1f[t] = b1p[t]; b2f[t] = b2p[t]; }
    if (t < 8) x_hwc[256*XROW + t] = 0;
  }
  __syncthreads();

  // ---------------- conv1: M=128(oc), N=196(pix)->13 tiles, K=144->160 ----------------
  const u16* W1b = w1p + bb * (128*160);
  f32x4 acc1[2][13];
  #pragma unroll
  for (int mi = 0; mi < 2; ++mi)
    #pragma unroll
    for (int nt = 0; nt < 13; ++nt) acc1[mi][nt] = zero4();

  int offb[13];                    // byte offset of pixel row in x_hwc
  #pragma unroll
  for (int nt = 0; nt < 13; ++nt) {
    int p = nt*16 + l15; if (p > 195) p = 195;
    int y = p / 14, x = p % 14;
    offb[nt] = (y*16 + x) * (XROW*2);
  }

  #pragma unroll
  for (int ks = 0; ks < 5; ++ks) {
    int k = ks*32 + lq*8;
    bf16x8 a0 = ld8(W1b + ((w*2 + 0)*16 + l15)*160 + k);
    bf16x8 a1 = ld8(W1b + ((w*2 + 1)*16 + l15)*160 + k);
    int kk = k >> 4;                 // 0..9 (9 => zero padding)
    int ky = kk / 3, kx = kk - ky*3;
    int koffB = (ky*16 + kx)*(XROW*2) + (k & 15)*2;
    bool kvalid = (k < 144);
    #pragma unroll
    for (int nt = 0; nt < 13; ++nt) {
      int byte = kvalid ? (offb[nt] + koffB) : (256*XROW*2);
      bf16x8 bf = ld8((const u16*)((const char*)x_hwc + byte));
      acc1[0][nt] = mfma16(a0, bf, acc1[0][nt]);
      acc1[1][nt] = mfma16(a1, bf, acc1[1][nt]);
    }
  }

  // bias + relu -> h1t [pixel][ic], b64 packed writes (conflict-free)
  {
    int oc0 = lq*4;   // within-16 row base; tile adds (w*2+mi)*16
    #pragma unroll
    for (int mi = 0; mi < 2; ++mi) {
      int ocb = (w*2 + mi)*16 + oc0;
      #pragma unroll
      for (int nt = 0; nt < 13; ++nt) {
        int p = nt*16 + l15;
        if (p < 196) {
          float r0 = acc1[mi][nt][0] + b1f[ocb+0]; r0 = r0 > 0.f ? r0 : 0.f;
          float r1 = acc1[mi][nt][1] + b1f[ocb+1]; r1 = r1 > 0.f ? r1 : 0.f;
          float r2 = acc1[mi][nt][2] + b1f[ocb+2]; r2 = r2 > 0.f ? r2 : 0.f;
          float r3 = acc1[mi][nt][3] + b1f[ocb+3]; r3 = r3 > 0.f ? r3 : 0.f;
          U32x2 val{ cvtpk(r0, r1), cvtpk(r2, r3) };
          int byte = p*256 + ((ocb*2) ^ ((p & 7) << 4));
          *(U32x2*)((char*)h1t + byte) = val;
        }
      }
    }
  }
  __syncthreads();

  // ---------------- conv2: M=128(oc), N=144(pix)->9 uniform-mod-8 tiles, K=1152 ----------------
  // tile map: nt<6: rows {nt, nt+6} x (x2=0..7); nt>=6: rows 4i..4i+3 x (x2=8..11)
  int ppb[9], p2o[9];
  #pragma unroll
  for (int nt = 0; nt < 9; ++nt) {
    int y2, x2;
    if (nt < 6) { y2 = nt + 6*(l15 >> 3); x2 = l15 & 7; }
    else        { y2 = (nt-6)*4 + (l15 >> 2); x2 = 8 + (l15 & 3); }
    ppb[nt] = y2*14 + x2;
    p2o[nt] = y2*12 + x2;
  }

  const u16* W2b = w2p + bb * (128*1152);
  f32x4 acc2[2][9];
  #pragma unroll
  for (int mi = 0; mi < 2; ++mi)
    #pragma unroll
    for (int nt = 0; nt < 9; ++nt) acc2[mi][nt] = zero4();

  const u16* A0p = W2b + ((w*2 + 0)*16 + l15)*1152;
  const u16* A1p = W2b + ((w*2 + 1)*16 + l15)*1152;
  bf16x8 a0 = ld8(A0p + lq*8);
  bf16x8 a1 = ld8(A1p + lq*8);
  int lq16 = lq*16;

  #pragma unroll
  for (int kk = 0; kk < 9; ++kk) {
    int ky = kk / 3, kx = kk - ky*3;
    int pkp = ky*14 + kx;
    int ax[9];
    #pragma unroll
    for (int nt = 0; nt < 9; ++nt) {
      int pp = ppb[nt] + pkp;
      ax[nt] = pp*256 + (lq16 ^ ((pp & 7) << 4));
    }
    #pragma unroll
    for (int s = 0; s < 4; ++s) {
      int ks = kk*4 + s;
      int k = ks*32 + lq*8;
      int kn = (ks < 35) ? (k + 32) : (lq*8);
      bf16x8 na0 = ld8(A0p + kn);
      bf16x8 na1 = ld8(A1p + kn);
      int kx6 = s << 6;
      #pragma unroll
      for (int nt = 0; nt < 9; ++nt) {
        bf16x8 bfr = ld8((const u16*)((const char*)h1t + (ax[nt] ^ kx6)));
        acc2[0][nt] = mfma16(a0, bfr, acc2[0][nt]);
        acc2[1][nt] = mfma16(a1, bfr, acc2[1][nt]);
      }
      a0 = na0; a1 = na1;
    }
  }

  u16* outp = bb == 0 ? outq : bb == 1 ? outk : outv;
  u16* oe = outp + (size_t)e * DFULL;
  #pragma unroll
  for (int mi = 0; mi < 2; ++mi) {
    int ocb = (w*2 + mi)*16 + lq*4;
    #pragma unroll
    for (int nt = 0; nt < 9; ++nt) {
      #pragma unroll
      for (int r = 0; r < 4; ++r) {
        float v = acc2[mi][nt][r] + b2f[ocb + r];
        v = v > 0.f ? v : 0.f;
        oe[(ocb + r)*144 + p2o[nt]] = f2bf(v);
      }
    }
  }
}

// ------------------------------------------------------------------
// S = Q K^T partials: grid (16 g x nc), each block K-chunk of 18432/nc
// ------------------------------------------------------------------
__global__ __launch_bounds__(256, 2)
void qk_partial(const u16* __restrict__ Q, const u16* __restrict__ K, float* __restrict__ Sp, int nc)
{
  const int g = blockIdx.x / nc, kc = blockIdx.x % nc;
  const int t = threadIdx.x, w = t >> 6, l = t & 63;
  const int l15 = l & 15, lq = l >> 4;
  const int CH = DFULL / nc;
  const u16* Qb = Q + (size_t)g*128*DFULL + kc*CH;
  const u16* Kb = K + (size_t)g*128*DFULL + kc*CH;

  f32x4 acc[2][8];
  #pragma unroll
  for (int mi = 0; mi < 2; ++mi)
    #pragma unroll
    for (int nt = 0; nt < 8; ++nt) acc[mi][nt] = zero4();

  for (int ks = 0; ks < CH/32; ++ks) {
    int k = ks*32 + lq*8;
    bf16x8 a0 = ld8(Qb + (size_t)((w*2 + 0)*16 + l15)*DFULL + k);
    bf16x8 a1 = ld8(Qb + (size_t)((w*2 + 1)*16 + l15)*DFULL + k);
    #pragma unroll
    for (int nt = 0; nt < 8; ++nt) {
      bf16x8 b = ld8(Kb + (size_t)(nt*16 + l15)*DFULL + k);
      acc[0][nt] = mfma16(a0, b, acc[0][nt]);
      acc[1][nt] = mfma16(a1, b, acc[1][nt]);
    }
  }

  float* So = Sp + (size_t)(g*nc + kc)*16384;
  #pragma unroll
  for (int mi = 0; mi < 2; ++mi)
    #pragma unroll
    for (int nt = 0; nt < 8; ++nt) {
      int col = nt*16 + l15;
      #pragma unroll
      for (int r = 0; r < 4; ++r) {
        int row = (w*2 + mi)*16 + lq*4 + r;
        So[row*128 + col] = acc[mi][nt][r];
      }
    }
}

// ------------------------------------------------------------------
// softmax: one wave per (g,n) row; reduce nc partials, scale=1/16
// ------------------------------------------------------------------
__global__ void softmax_p(const float* __restrict__ Sp, u16* __restrict__ P, int nc)
{
  const int rr = blockIdx.x;          // 2048 rows
  const int g = rr >> 7, n = rr & 127;
  const int l = threadIdx.x;          // 64
  const float* base = Sp + (size_t)g*nc*16384 + n*128;
  float v0 = 0.f, v1 = 0.f;
  for (int kc = 0; kc < nc; ++kc) {
    v0 += base[(size_t)kc*16384 + l];
    v1 += base[(size_t)kc*16384 + 64 + l];
  }
  v0 *= 0.0625f; v1 *= 0.0625f;       // scale = 1/sqrt(2*128)
  float m = fmaxf(v0, v1);
  #pragma unroll
  for (int s = 32; s; s >>= 1) m = fmaxf(m, __shfl_xor(m, s));
  float e0 = __expf(v0 - m), e1 = __expf(v1 - m);
  float sum = e0 + e1;
  #pragma unroll
  for (int s = 32; s; s >>= 1) sum += __shfl_xor(sum, s);
  float inv = 1.f / sum;
  u16* Pr = P + (size_t)g*16384 + n*128;
  Pr[l]      = f2bf(e0 * inv);
  Pr[64 + l] = f2bf(e1 * inv);
}

// ------------------------------------------------------------------
// O = P V: grid (16 g x 96 d-chunks of 192). V (bf16) in ws; O (f32) -> d_out.
// ------------------------------------------------------------------
__global__ __launch_bounds__(256, 2)
void pv_kernel(const u16* __restrict__ P, const u16* __restrict__ V, float* __restrict__ O)
{
  const int g  = blockIdx.x / 96;
  const int dc = blockIdx.x % 96;
  const int d0 = dc * 192;
  const int t = threadIdx.x, w = t >> 6, l = t & 63;
  const int l15 = l & 15, lq = l >> 4;

  __shared__ __align__(16) u16 Vl[128 * 196];   // stride 392B, 8B-aligned rows

  const u16* Vg = V + (size_t)g*128*DFULL + d0;
  for (int i = t; i < 6144; i += 256) {          // 8B units: 128 rows x 48
    int m = i / 48, c4 = (i % 48) * 4;
    *(US4*)(Vl + m*196 + c4) = *(const US4*)(Vg + (size_t)m*DFULL + c4);
  }
  __syncthreads();

  const u16* Pg = P + (size_t)g*16384;
  f32x4 acc[2][12];
  #pragma unroll
  for (int mi = 0; mi < 2; ++mi)
    #pragma unroll
    for (int nt = 0; nt < 12; ++nt) acc[mi][nt] = zero4();

  #pragma unroll
  for (int ks = 0; ks < 4; ++ks) {
    int k = ks*32 + lq*8;
    bf16x8 a0 = ld8(Pg + ((w*2 + 0)*16 + l15)*128 + k);
    bf16x8 a1 = ld8(Pg + ((w*2 + 1)*16 + l15)*128 + k);
    #pragma unroll
    for (int nt = 0; nt < 12; ++nt) {
      int d = nt*16 + l15;
      US8 tmp;
      #pragma unroll
      for (int j = 0; j < 8; ++j) tmp.s[j] = Vl[(k + j)*196 + d];
      bf16x8 b = __builtin_bit_cast(bf16x8, tmp);
      acc[0][nt] = mfma16(a0, b, acc[0][nt]);
      acc[1][nt] = mfma16(a1, b, acc[1][nt]);
    }
  }

  float* Og = O + (size_t)g*128*DFULL + d0;
  #pragma unroll
  for (int mi = 0; mi < 2; ++mi)
    #pragma unroll
    for (int nt = 0; nt < 12; ++nt) {
      int d = nt*16 + l15;
      #pragma unroll
      for (int r = 0; r < 4; ++r) {
        int n = (w*2 + mi)*16 + lq*4 + r;
        Og[(size_t)n*DFULL + d] = acc[mi][nt][r];
      }
    }
}

// ------------------------------------------------------------------
extern "C" void kernel_launch(void* const* d_in, const int* in_sizes, int n_in,
                              void* d_out, int out_size, void* d_ws, size_t ws_size,
                              hipStream_t stream)
{
  const float* edge_feat = (const float*)d_in[0];
  const float* qw1 = (const float*)d_in[2];
  const float* qb1 = (const float*)d_in[3];
  const float* qw2 = (const float*)d_in[4];
  const float* qb2 = (const float*)d_in[5];
  const float* kw1 = (const float*)d_in[6];
  const float* kb1 = (const float*)d_in[7];
  const float* kw2 = (const float*)d_in[8];
  const float* kb2 = (const float*)d_in[9];
  const float* vw1 = (const float*)d_in[10];
  const float* vb1 = (const float*)d_in[11];
  const float* vw2 = (const float*)d_in[12];
  const float* vb2 = (const float*)d_in[13];

  // d_out (f32, 150,994,944 B) hosts Q,K as bf16 during the pipeline,
  // then pv overwrites it with the f32 output.
  u16* Qd = (u16*)d_out;
  u16* Kd = (u16*)d_out + (size_t)NE*DFULL;

  // Workspace layout:
  char* ws = (char*)d_ws;
  u16*   W1p = (u16*)  (ws + 0);           //    122,880 B
  u16*   W2p = (u16*)  (ws + 122880);      //    884,736 B
  u16*   Vb  = (u16*)  (ws + 1007616);     // 75,497,472 B
  float* Sp  = (float*)(ws + 76505088);    //  up to 16,777,216 B
  // Choose split-K factor by available workspace (NC=16 fills 256 CUs).
  int nc = 16;
  size_t need16 = 76505088ull + (size_t)16*16*16384*4 + 524288;
  if (ws_size < need16) nc = 8;
  u16* P = (u16*)(ws + 76505088 + (size_t)16*nc*16384*4);

  prep_weights<<<240, 256, 0, stream>>>(qw1, kw1, vw1, qw2, kw2, vw2, W1p, W2p);
  conv_fused<<<3*NE, 256, 0, stream>>>(edge_feat, W1p, W2p,
                                       qb1, kb1, vb1, qb2, kb2, vb2,
                                       Qd, Kd, Vb);
  qk_partial<<<16*nc, 256, 0, stream>>>(Qd, Kd, Sp, nc);
  softmax_p<<<2048, 64, 0, stream>>>(Sp, P, nc);
  pv_kernel<<<16*96, 256, 0, stream>>>(P, Vb, (float*)d_out);
}